// Round 16
// baseline (116.405 us; speedup 1.0000x reference)
//
#include <hip/hip_runtime.h>

typedef _Float16 f16x8 __attribute__((ext_vector_type(8)));  // 8 f16 = 4 VGPRs
typedef __fp16  fp16x2 __attribute__((ext_vector_type(2)));  // pkrtz builtin's return type
typedef float f32x16 __attribute__((ext_vector_type(16)));

union FU { unsigned u[4]; f16x8 v; };

// v_cvt_pkrtz_f16_f32: two f32 -> packed 2xf16 (RTZ), ONE instruction.
__device__ __forceinline__ unsigned pkrtz(float a, float b) {
    union { fp16x2 h; unsigned u; } c;
    c.h = __builtin_amdgcn_cvt_pkrtz(a, b);
    return c.u;
}
__device__ __forceinline__ float f16bits_to_f32(unsigned u16bits) {
    union { unsigned short s; _Float16 h; } c; c.s = (unsigned short)u16bits;
    return (float)c.h;
}
// RTN pack (2 scalar cvt + pack) -- prologue/x-fold only
__device__ __forceinline__ unsigned pk_rtn(float a, float b) {
    union { _Float16 h[2]; unsigned u; } c;
    c.h[0] = (_Float16)a; c.h[1] = (_Float16)b;
    return c.u;
}

// tanh(a) given ap = 2*log2(e)*a:  tanh(a) = 1 - 2/(exp2(ap)+1)
__device__ __forceinline__ float tanh_fast(float ap) {
    float e = __builtin_amdgcn_exp2f(ap);
    return fmaf(-2.0f, __builtin_amdgcn_rcpf(e + 1.0f), 1.0f);
}

// R16 = R13 VERBATIM (best-known 41.9us: Whh hi/lo split 4-MFMA chain, dual
// f1a/f1b chains, xc preact fold, zeroC chain-start, fmaxf+pkrtz relu) with
// ONE isolated change: grid cap 1024 -> 2048 blocks (2 grid-stride iters per
// wave instead of 4). Theory: measured time-avg occupancy (~6 waves/CU vs 16
// static) is diluted by dispatch ramp + tail imbalance of long blocks; finer
// block granularity improves coverage at the cost of 2x prologue (~+7% issue).
// Decision rule pre-committed: >42us => R13's config is the plateau.
__global__ __launch_bounds__(256, 2)
void rnn_mlp_kernel(const float* __restrict__ x,
                    const float* __restrict__ wih, const float* __restrict__ whh,
                    const float* __restrict__ bih, const float* __restrict__ bhh,
                    const float* __restrict__ w1,  const float* __restrict__ b1,
                    const float* __restrict__ w2,  const float* __restrict__ b2,
                    const float* __restrict__ w3,  const float* __restrict__ b3,
                    float* __restrict__ out, int B)
{
    const float K = 2.8853900817779268f; // 2*log2(e)
    const int tid = threadIdx.x;
    const int wv = tid >> 6, l = tid & 63;
    const int n = l & 31, H = l >> 5;                     // n: acc col / A-row m; H: lane half

    // persistent zero accumulator (chain-start C operand)
    f32x16 zeroC;
    #pragma unroll
    for (int r = 0; r < 16; ++r) zeroC[r] = 0.f;

    // ---- one-time per-wave fragment build ----
    FU xcA;                                               // [wih*K | c*K] fold, rows m, k=0,1
    {
        const unsigned w0 = pkrtz(wih[n] * K, (bih[n] + bhh[n]) * K);
        xcA.u[0] = (H == 0) ? w0 : 0u;
        xcA.u[1] = 0u; xcA.u[2] = 0u; xcA.u[3] = 0u;
    }
    FU whhF[2][2];                                        // [k-half c][hi/lo split], exact Whh
    #pragma unroll
    for (int c = 0; c < 2; ++c)
        #pragma unroll
        for (int r = 0; r < 4; ++r) {
            const int j0 = c * 16 + 4 * H + 8 * (r >> 1) + 2 * (r & 1);
            const float a0 = whh[n * 32 + j0]     * K;
            const float a1 = whh[n * 32 + j0 + 1] * K;
            const unsigned hi = pkrtz(a0, a1);
            whhF[c][0].u[r] = hi;
            whhF[c][1].u[r] = pkrtz(a0 - f16bits_to_f32(hi & 0xffffu),
                                    a1 - f16bits_to_f32(hi >> 16));
        }
    FU w1F[3][2];                                         // [t][k-half c], single f16, rows>=16 zero
    #pragma unroll
    for (int tt = 0; tt < 3; ++tt)
        #pragma unroll
        for (int c = 0; c < 2; ++c)
            #pragma unroll
            for (int r = 0; r < 4; ++r) {
                const int j0 = c * 16 + 4 * H + 8 * (r >> 1) + 2 * (r & 1);
                const float a0 = (n < 16) ? w1[n * 96 + tt * 32 + j0]     : 0.f;
                const float a1 = (n < 16) ? w1[n * 96 + tt * 32 + j0 + 1] : 0.f;
                w1F[tt][c].u[r] = pkrtz(a0, a1);
            }
    FU w2F;                                               // fc2 A-frag (rows o>=8 zero), K=16
    #pragma unroll
    for (int r = 0; r < 4; ++r) {
        const int k0 = 4 * H + 8 * (r >> 1) + 2 * (r & 1);
        const float a0 = (n < 8) ? w2[n * 16 + k0]     : 0.f;
        const float a1 = (n < 8) ? w2[n * 16 + k0 + 1] : 0.f;
        w2F.u[r] = pkrtz(a0, a1);
    }
    float b2p[4], w3v[4];                                 // b2' = b2 + W2*b1 (b1 folded out)
    #pragma unroll
    for (int r = 0; r < 4; ++r) {
        const int o = r + 4 * H;
        float s = b2[o];
        #pragma unroll
        for (int k = 0; k < 16; ++k) s = fmaf(w2[o * 16 + k], b1[k], s);
        b2p[r] = s;
        w3v[r] = w3[o];
    }
    const float b3s = b3[0];

    const int WSTRIDE = gridDim.x * 4 * 64;               // 2 groups x 32 per wave-iter
    int base0 = (blockIdx.x * 4 + wv) * 64;

    // prefetch first iteration's x (both groups)
    float nx[2][3];
    #pragma unroll
    for (int z = 0; z < 2; ++z) {
        const int v = base0 + 32 * z + n;
        const int ix = (v < B) ? v : (B - 1);
        nx[z][0] = x[3*ix]; nx[z][1] = x[3*ix+1]; nx[z][2] = x[3*ix+2];
    }

    for (; base0 < B; base0 += WSTRIDE) {
        float xv[2][3];
        #pragma unroll
        for (int z = 0; z < 2; ++z) {
            xv[z][0] = nx[z][0]; xv[z][1] = nx[z][1]; xv[z][2] = nx[z][2];
        }

        // issue next iteration's x loads now; latency hides under compute
        const int nb = base0 + WSTRIDE;                   // wave-uniform branch
        if (nb < B) {
            #pragma unroll
            for (int z = 0; z < 2; ++z) {
                const int v = nb + 32 * z + n;
                const int ix = (v < B) ? v : (B - 1);
                nx[z][0] = x[3*ix]; nx[z][1] = x[3*ix+1]; nx[z][2] = x[3*ix+2];
            }
        }

        f32x16 f1a[2], f1b[2];                            // chain-started from zeroC at t=0
        FU hF[2][2];                                      // [group][k-half]

        #pragma unroll
        for (int t = 0; t < 3; ++t) {
            // pre-activation via xc-MFMA (B = [x_t; 1] at k=0,1; H=0 lanes only)
            f32x16 av[2];
            #pragma unroll
            for (int z = 0; z < 2; ++z) {
                FU xcB;
                const unsigned w0 = pk_rtn(xv[z][t], 1.0f);   // RTN for x accuracy
                xcB.u[0] = (H == 0) ? w0 : 0u;
                xcB.u[1] = 0u; xcB.u[2] = 0u; xcB.u[3] = 0u;
                av[z] = __builtin_amdgcn_mfma_f32_32x32x16_f16(xcA.v, xcB.v, zeroC, 0,0,0);
            }
            if (t > 0) {
                // two INDEPENDENT 4-MFMA chains (one per group) -> ILP
                #pragma unroll
                for (int z = 0; z < 2; ++z) {
                    av[z] = __builtin_amdgcn_mfma_f32_32x32x16_f16(whhF[0][0].v, hF[z][0].v, av[z], 0,0,0);
                    av[z] = __builtin_amdgcn_mfma_f32_32x32x16_f16(whhF[0][1].v, hF[z][0].v, av[z], 0,0,0);
                    av[z] = __builtin_amdgcn_mfma_f32_32x32x16_f16(whhF[1][0].v, hF[z][1].v, av[z], 0,0,0);
                    av[z] = __builtin_amdgcn_mfma_f32_32x32x16_f16(whhF[1][1].v, hF[z][1].v, av[z], 0,0,0);
                }
            }

            FU rF[2][2];
            #pragma unroll
            for (int z = 0; z < 2; ++z) {
                float h[16];
                #pragma unroll
                for (int r = 0; r < 16; ++r) h[r] = tanh_fast(av[z][r]);
                // B-frag elem i of half c == value at reg i+8c (same-lane identity)
                #pragma unroll
                for (int c = 0; c < 2; ++c)
                    #pragma unroll
                    for (int w = 0; w < 4; ++w) {
                        const float v0 = h[2*w + 8*c], v1 = h[2*w + 8*c + 1];
                        if (t < 2) hF[z][c].u[w] = pkrtz(v0, v1);
                        rF[z][c].u[w] = pkrtz(fmaxf(v0, 0.f), fmaxf(v1, 0.f));
                    }
            }

            #pragma unroll
            for (int z = 0; z < 2; ++z) {
                if (t == 0) {
                    f1a[z] = __builtin_amdgcn_mfma_f32_32x32x16_f16(w1F[t][0].v, rF[z][0].v, zeroC, 0,0,0);
                    f1b[z] = __builtin_amdgcn_mfma_f32_32x32x16_f16(w1F[t][1].v, rF[z][1].v, zeroC, 0,0,0);
                } else {
                    f1a[z] = __builtin_amdgcn_mfma_f32_32x32x16_f16(w1F[t][0].v, rF[z][0].v, f1a[z], 0,0,0);
                    f1b[z] = __builtin_amdgcn_mfma_f32_32x32x16_f16(w1F[t][1].v, rF[z][1].v, f1b[z], 0,0,0);
                }
            }
        }

        // fc2 via ONE MFMA per group (C-in = zeroC), then fc3 on VALU
        #pragma unroll
        for (int z = 0; z < 2; ++z) {
            FU bB;
            #pragma unroll
            for (int w = 0; w < 4; ++w)
                bB.u[w] = pkrtz(f1a[z][2*w] + f1b[z][2*w], f1a[z][2*w+1] + f1b[z][2*w+1]);
            f32x16 gacc = __builtin_amdgcn_mfma_f32_32x32x16_f16(w2F.v, bB.v, zeroC, 0,0,0);

            float p = 0.f;
            #pragma unroll
            for (int r = 0; r < 4; ++r)                   // lane holds g rows r+4H
                p = fmaf(fmaxf(gacc[r] + b2p[r], 0.f), w3v[r], p);
            const float y = p + __shfl_xor(p, 32) + b3s;
            const int idx = base0 + 32 * z + n;
            if (H == 0 && idx < B) out[idx] = y;
        }
    }
}

extern "C" void kernel_launch(void* const* d_in, const int* in_sizes, int n_in,
                              void* d_out, int out_size, void* d_ws, size_t ws_size,
                              hipStream_t stream)
{
    const float* x   = (const float*)d_in[0];
    const float* wih = (const float*)d_in[1];
    const float* whh = (const float*)d_in[2];
    const float* bih = (const float*)d_in[3];
    const float* bhh = (const float*)d_in[4];
    const float* w1  = (const float*)d_in[5];
    const float* b1  = (const float*)d_in[6];
    const float* w2  = (const float*)d_in[7];
    const float* b2  = (const float*)d_in[8];
    const float* w3  = (const float*)d_in[9];
    const float* b3  = (const float*)d_in[10];
    float* out = (float*)d_out;

    const int B = in_sizes[0] / 3;

    int blocks = (B + 255) / 256;                 // 4 waves/block, 64 elem/wave/iter
    if (blocks > 2048) blocks = 2048;             // A/B vs R13: 8 blocks/CU, 2 iters/wave
    rnn_mlp_kernel<<<blocks, 256, 0, stream>>>(x, wih, whh, bih, bhh,
                                               w1, b1, w2, b2, w3, b3, out, B);
}

// Round 17
// 113.032 us; speedup vs baseline: 1.0298x; 1.0298x over previous
//
#include <hip/hip_runtime.h>

typedef _Float16 f16x8 __attribute__((ext_vector_type(8)));  // 8 f16 = 4 VGPRs
typedef __fp16  fp16x2 __attribute__((ext_vector_type(2)));  // pkrtz builtin's return type
typedef float f32x16 __attribute__((ext_vector_type(16)));

union FU { unsigned u[4]; f16x8 v; };

// v_cvt_pkrtz_f16_f32: two f32 -> packed 2xf16 (RTZ), ONE instruction.
__device__ __forceinline__ unsigned pkrtz(float a, float b) {
    union { fp16x2 h; unsigned u; } c;
    c.h = __builtin_amdgcn_cvt_pkrtz(a, b);
    return c.u;
}
__device__ __forceinline__ float f16bits_to_f32(unsigned u16bits) {
    union { unsigned short s; _Float16 h; } c; c.s = (unsigned short)u16bits;
    return (float)c.h;
}
// RTN pack (2 scalar cvt + pack) -- prologue/x-fold only
__device__ __forceinline__ unsigned pk_rtn(float a, float b) {
    union { _Float16 h[2]; unsigned u; } c;
    c.h[0] = (_Float16)a; c.h[1] = (_Float16)b;
    return c.u;
}

// tanh(a) given ap = 2*log2(e)*a:  tanh(a) = 1 - 2/(exp2(ap)+1)
__device__ __forceinline__ float tanh_fast(float ap) {
    float e = __builtin_amdgcn_exp2f(ap);
    return fmaf(-2.0f, __builtin_amdgcn_rcpf(e + 1.0f), 1.0f);
}

// FINAL = R13 config (measured best: 41.9us dispatch). Structure:
// - One wave = 2 independent 32-element groups (N-dim of mfma_f32_32x32x16_f16)
// - Preact (Wih*x + bias) folded into one K=16 MFMA (A=[wih*K|c*K|0..],
//   B=[x;1;0..] at k-slots 0,1; H=0 lanes only)
// - Whh as hi+lo split f16 A-frags (exact to ~2^-22), 4-MFMA chain per group;
//   these "extra" MFMAs are free latency fillers (R14: deleting them LOST 11%)
// - tanh in-register on acc layout; B-frag elem i of half c == acc reg i+8c
//   (same-lane identity; LDS round-trip proven identity and deleted in R7)
// - fc1 via 2 MFMA chains/group (f1a/f1b); fc2 = ONE MFMA (f1 acc regs 0..7
//   == B-frag k-layout); b1 folded into b2' = b2 + W2*b1; fc3 = 4 fma + shfl
// - zeroC persistent chain-start C operand (kills ~96 movs/iter)
// - grid 1024 blocks = 4/CU (2048 regressed 12% -- prologue dominates; R16)
// A/B'd neutral-or-negative and therefore absent: x-prefetch depth>1 (R11),
// pk_max relu (R15), op-thinning (R14), NG=4 (R4-era), 2048 blocks (R16).
__global__ __launch_bounds__(256, 2)
void rnn_mlp_kernel(const float* __restrict__ x,
                    const float* __restrict__ wih, const float* __restrict__ whh,
                    const float* __restrict__ bih, const float* __restrict__ bhh,
                    const float* __restrict__ w1,  const float* __restrict__ b1,
                    const float* __restrict__ w2,  const float* __restrict__ b2,
                    const float* __restrict__ w3,  const float* __restrict__ b3,
                    float* __restrict__ out, int B)
{
    const float K = 2.8853900817779268f; // 2*log2(e)
    const int tid = threadIdx.x;
    const int wv = tid >> 6, l = tid & 63;
    const int n = l & 31, H = l >> 5;                     // n: acc col / A-row m; H: lane half

    // persistent zero accumulator (chain-start C operand)
    f32x16 zeroC;
    #pragma unroll
    for (int r = 0; r < 16; ++r) zeroC[r] = 0.f;

    // ---- one-time per-wave fragment build ----
    FU xcA;                                               // [wih*K | c*K] fold, rows m, k=0,1
    {
        const unsigned w0 = pkrtz(wih[n] * K, (bih[n] + bhh[n]) * K);
        xcA.u[0] = (H == 0) ? w0 : 0u;
        xcA.u[1] = 0u; xcA.u[2] = 0u; xcA.u[3] = 0u;
    }
    FU whhF[2][2];                                        // [k-half c][hi/lo split], exact Whh
    #pragma unroll
    for (int c = 0; c < 2; ++c)
        #pragma unroll
        for (int r = 0; r < 4; ++r) {
            const int j0 = c * 16 + 4 * H + 8 * (r >> 1) + 2 * (r & 1);
            const float a0 = whh[n * 32 + j0]     * K;
            const float a1 = whh[n * 32 + j0 + 1] * K;
            const unsigned hi = pkrtz(a0, a1);
            whhF[c][0].u[r] = hi;
            whhF[c][1].u[r] = pkrtz(a0 - f16bits_to_f32(hi & 0xffffu),
                                    a1 - f16bits_to_f32(hi >> 16));
        }
    FU w1F[3][2];                                         // [t][k-half c], single f16, rows>=16 zero
    #pragma unroll
    for (int tt = 0; tt < 3; ++tt)
        #pragma unroll
        for (int c = 0; c < 2; ++c)
            #pragma unroll
            for (int r = 0; r < 4; ++r) {
                const int j0 = c * 16 + 4 * H + 8 * (r >> 1) + 2 * (r & 1);
                const float a0 = (n < 16) ? w1[n * 96 + tt * 32 + j0]     : 0.f;
                const float a1 = (n < 16) ? w1[n * 96 + tt * 32 + j0 + 1] : 0.f;
                w1F[tt][c].u[r] = pkrtz(a0, a1);
            }
    FU w2F;                                               // fc2 A-frag (rows o>=8 zero), K=16
    #pragma unroll
    for (int r = 0; r < 4; ++r) {
        const int k0 = 4 * H + 8 * (r >> 1) + 2 * (r & 1);
        const float a0 = (n < 8) ? w2[n * 16 + k0]     : 0.f;
        const float a1 = (n < 8) ? w2[n * 16 + k0 + 1] : 0.f;
        w2F.u[r] = pkrtz(a0, a1);
    }
    float b2p[4], w3v[4];                                 // b2' = b2 + W2*b1 (b1 folded out)
    #pragma unroll
    for (int r = 0; r < 4; ++r) {
        const int o = r + 4 * H;
        float s = b2[o];
        #pragma unroll
        for (int k = 0; k < 16; ++k) s = fmaf(w2[o * 16 + k], b1[k], s);
        b2p[r] = s;
        w3v[r] = w3[o];
    }
    const float b3s = b3[0];

    const int WSTRIDE = gridDim.x * 4 * 64;               // 2 groups x 32 per wave-iter
    int base0 = (blockIdx.x * 4 + wv) * 64;

    // prefetch first iteration's x (both groups)
    float nx[2][3];
    #pragma unroll
    for (int z = 0; z < 2; ++z) {
        const int v = base0 + 32 * z + n;
        const int ix = (v < B) ? v : (B - 1);
        nx[z][0] = x[3*ix]; nx[z][1] = x[3*ix+1]; nx[z][2] = x[3*ix+2];
    }

    for (; base0 < B; base0 += WSTRIDE) {
        float xv[2][3];
        #pragma unroll
        for (int z = 0; z < 2; ++z) {
            xv[z][0] = nx[z][0]; xv[z][1] = nx[z][1]; xv[z][2] = nx[z][2];
        }

        // issue next iteration's x loads now; latency hides under compute
        const int nb = base0 + WSTRIDE;                   // wave-uniform branch
        if (nb < B) {
            #pragma unroll
            for (int z = 0; z < 2; ++z) {
                const int v = nb + 32 * z + n;
                const int ix = (v < B) ? v : (B - 1);
                nx[z][0] = x[3*ix]; nx[z][1] = x[3*ix+1]; nx[z][2] = x[3*ix+2];
            }
        }

        f32x16 f1a[2], f1b[2];                            // chain-started from zeroC at t=0
        FU hF[2][2];                                      // [group][k-half]

        #pragma unroll
        for (int t = 0; t < 3; ++t) {
            // pre-activation via xc-MFMA (B = [x_t; 1] at k=0,1; H=0 lanes only)
            f32x16 av[2];
            #pragma unroll
            for (int z = 0; z < 2; ++z) {
                FU xcB;
                const unsigned w0 = pk_rtn(xv[z][t], 1.0f);   // RTN for x accuracy
                xcB.u[0] = (H == 0) ? w0 : 0u;
                xcB.u[1] = 0u; xcB.u[2] = 0u; xcB.u[3] = 0u;
                av[z] = __builtin_amdgcn_mfma_f32_32x32x16_f16(xcA.v, xcB.v, zeroC, 0,0,0);
            }
            if (t > 0) {
                // two INDEPENDENT 4-MFMA chains (one per group) -> ILP
                #pragma unroll
                for (int z = 0; z < 2; ++z) {
                    av[z] = __builtin_amdgcn_mfma_f32_32x32x16_f16(whhF[0][0].v, hF[z][0].v, av[z], 0,0,0);
                    av[z] = __builtin_amdgcn_mfma_f32_32x32x16_f16(whhF[0][1].v, hF[z][0].v, av[z], 0,0,0);
                    av[z] = __builtin_amdgcn_mfma_f32_32x32x16_f16(whhF[1][0].v, hF[z][1].v, av[z], 0,0,0);
                    av[z] = __builtin_amdgcn_mfma_f32_32x32x16_f16(whhF[1][1].v, hF[z][1].v, av[z], 0,0,0);
                }
            }

            FU rF[2][2];
            #pragma unroll
            for (int z = 0; z < 2; ++z) {
                float h[16];
                #pragma unroll
                for (int r = 0; r < 16; ++r) h[r] = tanh_fast(av[z][r]);
                // B-frag elem i of half c == value at reg i+8c (same-lane identity)
                #pragma unroll
                for (int c = 0; c < 2; ++c)
                    #pragma unroll
                    for (int w = 0; w < 4; ++w) {
                        const float v0 = h[2*w + 8*c], v1 = h[2*w + 8*c + 1];
                        if (t < 2) hF[z][c].u[w] = pkrtz(v0, v1);
                        rF[z][c].u[w] = pkrtz(fmaxf(v0, 0.f), fmaxf(v1, 0.f));
                    }
            }

            #pragma unroll
            for (int z = 0; z < 2; ++z) {
                if (t == 0) {
                    f1a[z] = __builtin_amdgcn_mfma_f32_32x32x16_f16(w1F[t][0].v, rF[z][0].v, zeroC, 0,0,0);
                    f1b[z] = __builtin_amdgcn_mfma_f32_32x32x16_f16(w1F[t][1].v, rF[z][1].v, zeroC, 0,0,0);
                } else {
                    f1a[z] = __builtin_amdgcn_mfma_f32_32x32x16_f16(w1F[t][0].v, rF[z][0].v, f1a[z], 0,0,0);
                    f1b[z] = __builtin_amdgcn_mfma_f32_32x32x16_f16(w1F[t][1].v, rF[z][1].v, f1b[z], 0,0,0);
                }
            }
        }

        // fc2 via ONE MFMA per group (C-in = zeroC), then fc3 on VALU
        #pragma unroll
        for (int z = 0; z < 2; ++z) {
            FU bB;
            #pragma unroll
            for (int w = 0; w < 4; ++w)
                bB.u[w] = pkrtz(f1a[z][2*w] + f1b[z][2*w], f1a[z][2*w+1] + f1b[z][2*w+1]);
            f32x16 gacc = __builtin_amdgcn_mfma_f32_32x32x16_f16(w2F.v, bB.v, zeroC, 0,0,0);

            float p = 0.f;
            #pragma unroll
            for (int r = 0; r < 4; ++r)                   // lane holds g rows r+4H
                p = fmaf(fmaxf(gacc[r] + b2p[r], 0.f), w3v[r], p);
            const float y = p + __shfl_xor(p, 32) + b3s;
            const int idx = base0 + 32 * z + n;
            if (H == 0 && idx < B) out[idx] = y;
        }
    }
}

extern "C" void kernel_launch(void* const* d_in, const int* in_sizes, int n_in,
                              void* d_out, int out_size, void* d_ws, size_t ws_size,
                              hipStream_t stream)
{
    const float* x   = (const float*)d_in[0];
    const float* wih = (const float*)d_in[1];
    const float* whh = (const float*)d_in[2];
    const float* bih = (const float*)d_in[3];
    const float* bhh = (const float*)d_in[4];
    const float* w1  = (const float*)d_in[5];
    const float* b1  = (const float*)d_in[6];
    const float* w2  = (const float*)d_in[7];
    const float* b2  = (const float*)d_in[8];
    const float* w3  = (const float*)d_in[9];
    const float* b3  = (const float*)d_in[10];
    float* out = (float*)d_out;

    const int B = in_sizes[0] / 3;

    int blocks = (B + 255) / 256;                 // 4 waves/block, 64 elem/wave/iter
    if (blocks > 1024) blocks = 1024;             // 4 blocks/CU (R13 config; 2048 = -12%, R16)
    rnn_mlp_kernel<<<blocks, 256, 0, stream>>>(x, wih, whh, bih, bhh,
                                               w1, b1, w2, b2, w3, b3, out, B);
}